// Round 14
// baseline (333.924 us; speedup 1.0000x reference)
//
#include <hip/hip_runtime.h>

typedef _Float16 f16;
typedef f16  f16x4 __attribute__((ext_vector_type(4)));
typedef f16  f16x8 __attribute__((ext_vector_type(8)));
typedef float f32x4 __attribute__((ext_vector_type(4)));

#define B_  64
#define S_  2048
#define H_  512
#define K_  1024   // 2H

__device__ __forceinline__ float fast_tanh(float x){
  float ax = fabsf(x);
  float t  = __expf(-2.0f*ax);
  float r  = (1.0f - t) / (1.0f + t);
  return x < 0.0f ? -r : r;
}

// ---- k0: fused {We repack} + {dec_proj GEMV} + {C = sum|v|} ---------------
__global__ __launch_bounds__(256) void prep_k(const float* __restrict__ We,
                                              f16* __restrict__ Bg,
                                              const float* __restrict__ dh,
                                              const float* __restrict__ Wd,
                                              float* __restrict__ dp,
                                              const float* __restrict__ vvg,
                                              float* __restrict__ vC){
  __shared__ float s_dh[512];
  if (blockIdx.x < 2048){
    int idx = blockIdx.x*256 + threadIdx.x;      // 0..524287
    int k = idx >> 9, col = idx & 511;
    Bg[((k>>3)<<12) + (col<<3) + (k&7)] = (f16)We[idx];
  } else if (blockIdx.x < 2176){
    int idx = blockIdx.x - 2048;                 // 0..127
    int b = idx >> 1, cg = idx & 1;
    int col = (cg<<8) + threadIdx.x;
    for (int i = threadIdx.x; i < 512; i += 256) s_dh[i] = dh[(b<<9) + i];
    __syncthreads();
    float a0=0.f,a1=0.f,a2=0.f,a3=0.f;
    for (int k = 0; k < 512; k += 4){
      a0 += s_dh[k+0]*Wd[(k+0)*512 + col];
      a1 += s_dh[k+1]*Wd[(k+1)*512 + col];
      a2 += s_dh[k+2]*Wd[(k+2)*512 + col];
      a3 += s_dh[k+3]*Wd[(k+3)*512 + col];
    }
    dp[(b<<9) + col] = (a0+a1)+(a2+a3);
  } else {
    // C = sum_h |v_h| : guaranteed upper bound on |score| since |tanh|<=1
    int t = threadIdx.x;
    float a = fabsf(vvg[t]) + fabsf(vvg[t+256]);
    #pragma unroll
    for (int o = 32; o >= 1; o >>= 1) a += __shfl_xor(a, o);
    if ((t & 63) == 0) s_dh[t>>6] = a;
    __syncthreads();
    if (t == 0) vC[0] = s_dh[0]+s_dh[1]+s_dh[2]+s_dh[3];
  }
}

// ---- k1: fused scores + unnorm-softmax + ctx partials ----
// R12: 256 thr / 4 waves, per-wave 64x128 (acc[4][8]); B SINGLE-buffered
// (32 KB) + A LDS-dbuf (8 KB) => ~40 KB LDS => 3 blocks/CU; independent
// blocks overlap each other's staging drains (m97/m114 mechanism).
__global__ __launch_bounds__(256, 3) void fused_k(
    const float* __restrict__ enc,   // [64][2048][1024] f32
    const f16*   __restrict__ Bg,    // [128][512][8] f16
    const float* __restrict__ dp,    // [64][512]
    const float* __restrict__ vvg,   // [512]
    const float* __restrict__ vC,    // [1]  shift C
    const int*   __restrict__ mask,  // [64][2048]
    float*       __restrict__ pbuf,  // [64][2048]  unnormalized exp
    float*       __restrict__ denom, // [64][32]    partial sums of p
    float*       __restrict__ part)  // [2048][1024] unnormalized ctx partials
{
  __shared__ __align__(16) f16 At[2][2048];    // [g4][row64 ^ (g<<2)][8]
  __shared__ __align__(16) f16 Bt[16384];      // single: [g4][col512][8]
  __shared__ float s_sc[64];

  const int tid  = threadIdx.x;
  const int lane = tid & 63;
  const int wave = tid >> 6;                   // 0..3
  const int b    = blockIdx.x >> 5;
  const int s0   = (blockIdx.x & 31) << 6;

  if (tid < 64) s_sc[tid] = 0.0f;

  // A staging: thread -> row = tid>>2 (0..63), g = tid&3 (k-octet), 8 f32
  const int arow = tid >> 2;
  const int ag   = tid & 3;
  const float* aG = enc + ((size_t)(b*S_ + s0 + arow) << 10) + (ag << 3);
  const int aDst = (ag << 9) + ((arow ^ (ag << 2)) << 3);   // halves

  // fragment read offsets
  const int r16 = lane & 15, g = lane >> 4;
  const int colb = wave << 7;                  // 128 cols per wave

  f32x4 acc[4][8] = {};

  auto stageB = [&](int t){
    const f16* src = Bg + ((size_t)t << 14);
    #pragma unroll
    for (int i = 0; i < 8; ++i){
      int slot = (i << 8) + tid;
      __builtin_amdgcn_global_load_lds(
          (const __attribute__((address_space(1))) void*)(src + (slot<<3)),
          (__attribute__((address_space(3))) void*)(&Bt[slot<<3]),
          16, 0, 0);
    }
  };
  struct A8 { f32x4 lo, hi; };
  auto loadA = [&](int t)->A8 {
    const float* p = aG + (t<<5);
    A8 r; r.lo = *(const f32x4*)p; r.hi = *(const f32x4*)(p+4); return r;
  };
  auto putA = [&](A8 a, int buf){
    f16x8 h;
    h[0]=(f16)a.lo[0]; h[1]=(f16)a.lo[1]; h[2]=(f16)a.lo[2]; h[3]=(f16)a.lo[3];
    h[4]=(f16)a.hi[0]; h[5]=(f16)a.hi[1]; h[6]=(f16)a.hi[2]; h[7]=(f16)a.hi[3];
    *(f16x8*)&At[buf][aDst] = h;
  };

  // prologue: stage B(0), A(0); then prefetch A(1)
  stageB(0);
  A8 aR = loadA(0);
  putA(aR, 0);
  __syncthreads();                 // drains vmcnt+lgkm: B(0), A(0) landed
  aR = loadA(1);

  for (int t = 0; t < 32; ++t){
    const int cur = t & 1;
    // compute step t from At[cur], Bt
    f16x8 af[4];
    #pragma unroll
    for (int m = 0; m < 4; ++m)
      af[m] = *(const f16x8*)&At[cur][(g<<9) + ((((m<<4)+r16) ^ (g<<2))<<3)];
    #pragma unroll
    for (int n = 0; n < 8; ++n){
      f16x8 bfr = *(const f16x8*)&Bt[(g<<12) + ((colb + (n<<4) + r16)<<3)];
      #pragma unroll
      for (int m = 0; m < 4; ++m)
        acc[m][n] = __builtin_amdgcn_mfma_f32_16x16x32_f16(af[m], bfr, acc[m][n], 0, 0, 0);
    }
    if (t < 31){
      putA(aR, cur^1);             // A(t+1) -> other A-buf (safe: past readers done)
      __syncthreads();             // all waves done reading Bt
      stageB(t+1);                 // overwrite single B buffer
      __syncthreads();             // B(t+1) + A(t+1) landed (vmcnt0+lgkm0)
      aR = loadA(t+2 <= 31 ? t+2 : 31);   // prefetch next A (dummy at t=30)
    }
  }

  // epilogue: e = tanh(acc + dp[col]); score_row += v[col]*e
  float dpv[8], vvv[8];
  #pragma unroll
  for (int n = 0; n < 8; ++n){
    int c = colb + (n<<4) + r16;
    dpv[n] = dp[(b<<9) + c];
    vvv[n] = vvg[c];
  }
  float sp[4][4];
  #pragma unroll
  for (int m = 0; m < 4; ++m)
    #pragma unroll
    for (int r = 0; r < 4; ++r) sp[m][r] = 0.f;
  #pragma unroll
  for (int m = 0; m < 4; ++m)
    #pragma unroll
    for (int n = 0; n < 8; ++n)
      #pragma unroll
      for (int r = 0; r < 4; ++r){
        float e = fast_tanh(acc[m][n][r] + dpv[n]);
        sp[m][r] += vvv[n]*e;
      }
  __syncthreads();                 // s_sc init visible (and all compute done)
  #pragma unroll
  for (int m = 0; m < 4; ++m)
    #pragma unroll
    for (int r = 0; r < 4; ++r){
      float x = sp[m][r];
      x += __shfl_xor(x, 1);
      x += __shfl_xor(x, 2);
      x += __shfl_xor(x, 4);
      x += __shfl_xor(x, 8);
      if (r16 == 0) atomicAdd(&s_sc[(m<<4) + (g<<2) + r], x);
    }
  __syncthreads();

  // p = mask ? exp(score - C) : 0 ; denom partial; overwrite s_sc with p
  const float C = vC[0];
  if (tid < 64){
    float s = s_sc[tid];
    int mk = mask[(b<<11) + s0 + tid];
    float p = mk ? __expf(s - C) : 0.0f;
    s_sc[tid] = p;
    pbuf[(b<<11) + s0 + tid] = p;
    float d = p;
    #pragma unroll
    for (int o = 32; o >= 1; o >>= 1) d += __shfl_xor(d, o);
    if (tid == 0) denom[(b<<5) + (blockIdx.x & 31)] = d;
  }
  __syncthreads();

  // context partial: part[blk][c] = sum_{s=0..63} p_s * enc[b][s0+s][c]
  {
    const f32x4* e4 = (const f32x4*)(enc + ((size_t)(b*S_ + s0) << 10)) + tid;
    f32x4 acc4 = {0.f,0.f,0.f,0.f};
    #pragma unroll 4
    for (int s = 0; s < 64; ++s){
      float w = s_sc[s];
      f32x4 x = e4[s*256];
      acc4 += w * x;
    }
    ((f32x4*)part)[(blockIdx.x<<8) + tid] = acc4;
  }
}

// ---- k2: combine: D = sum denom; ctx = sum part / D; attn = pbuf / D ----
__global__ __launch_bounds__(256) void combine_k(const float* __restrict__ part,
                                                 const float* __restrict__ denom,
                                                 const float* __restrict__ pbuf,
                                                 float* __restrict__ ctx,
                                                 float* __restrict__ attn){
  const int b = blockIdx.x, tid = threadIdx.x;
  float D = 0.f;
  #pragma unroll
  for (int c = 0; c < 32; ++c) D += denom[(b<<5) + c];
  D = fmaxf(D, 1e-37f);
  const float inv = 1.0f / D;

  f32x4 acc = {0.f,0.f,0.f,0.f};
  const f32x4* p4 = (const f32x4*)part;
  #pragma unroll
  for (int c = 0; c < 32; ++c)
    acc += p4[(((b<<5)+c)<<8) + tid];
  ((f32x4*)ctx)[(b<<8) + tid] = acc * inv;

  #pragma unroll
  for (int i = 0; i < 8; ++i){
    int s = tid + (i<<8);
    attn[(b<<11) + s] = pbuf[(b<<11) + s] * inv;
  }
}

extern "C" void kernel_launch(void* const* d_in, const int* in_sizes, int n_in,
                              void* d_out, int out_size, void* d_ws, size_t ws_size,
                              hipStream_t stream){
  (void)in_sizes; (void)n_in; (void)out_size;
  // ws layout (bytes):
  //   Bg    @ 0         : 1048576   (f16 repacked We)
  //   dproj @ 1048576   : 131072
  //   vC    @ 1179648   : 256
  //   pbuf  @ 1179904   : 524288
  //   denom @ 1704192   : 8192
  //   part  @ 1712384   : 8388608
  const size_t WS_NEED = 1712384u + 8388608u;   // ~9.63 MB
  if (ws_size < WS_NEED) return;

  const float* dec_h = (const float*)d_in[0];
  const float* enc   = (const float*)d_in[1];
  const int*   mask  = (const int*)d_in[2];
  const float* Wd    = (const float*)d_in[3];
  const float* We    = (const float*)d_in[4];
  const float* v     = (const float*)d_in[5];
  float* out  = (float*)d_out;
  float* ctx  = out;                       // [64][1024]
  float* attn = out + B_*2*H_;             // [64][2048]

  char* ws = (char*)d_ws;
  f16*   Bg     = (f16*)ws;
  float* dproj  = (float*)(ws + 1048576);
  float* vC     = (float*)(ws + 1179648);
  float* pbuf   = (float*)(ws + 1179904);
  float* denom  = (float*)(ws + 1704192);
  float* part   = (float*)(ws + 1712384);

  prep_k   <<<2177, 256, 0, stream>>>(We, Bg, dec_h, Wd, dproj, v, vC);
  fused_k  <<<2048, 256, 0, stream>>>(enc, Bg, dproj, v, vC, mask, pbuf, denom, part);
  combine_k<<<B_, 256, 0, stream>>>(part, denom, pbuf, ctx, attn);
}

// Round 15
// 316.601 us; speedup vs baseline: 1.0547x; 1.0547x over previous
//
#include <hip/hip_runtime.h>

typedef _Float16 f16;
typedef f16  f16x4 __attribute__((ext_vector_type(4)));
typedef f16  f16x8 __attribute__((ext_vector_type(8)));
typedef float f32x4 __attribute__((ext_vector_type(4)));

#define B_  64
#define S_  2048
#define H_  512
#define K_  1024   // 2H

__device__ __forceinline__ float fast_tanh(float x){
  float ax = fabsf(x);
  float t  = __expf(-2.0f*ax);
  float r  = (1.0f - t) / (1.0f + t);
  return x < 0.0f ? -r : r;
}

// ---- k0: fused {We repack} + {dec_proj GEMV} + {C = sum|v|} ---------------
__global__ __launch_bounds__(256) void prep_k(const float* __restrict__ We,
                                              f16* __restrict__ Bg,
                                              const float* __restrict__ dh,
                                              const float* __restrict__ Wd,
                                              float* __restrict__ dp,
                                              const float* __restrict__ vvg,
                                              float* __restrict__ vC){
  __shared__ float s_dh[512];
  if (blockIdx.x < 2048){
    int idx = blockIdx.x*256 + threadIdx.x;      // 0..524287
    int k = idx >> 9, col = idx & 511;
    Bg[((k>>3)<<12) + (col<<3) + (k&7)] = (f16)We[idx];
  } else if (blockIdx.x < 2176){
    int idx = blockIdx.x - 2048;                 // 0..127
    int b = idx >> 1, cg = idx & 1;
    int col = (cg<<8) + threadIdx.x;
    for (int i = threadIdx.x; i < 512; i += 256) s_dh[i] = dh[(b<<9) + i];
    __syncthreads();
    float a0=0.f,a1=0.f,a2=0.f,a3=0.f;
    for (int k = 0; k < 512; k += 4){
      a0 += s_dh[k+0]*Wd[(k+0)*512 + col];
      a1 += s_dh[k+1]*Wd[(k+1)*512 + col];
      a2 += s_dh[k+2]*Wd[(k+2)*512 + col];
      a3 += s_dh[k+3]*Wd[(k+3)*512 + col];
    }
    dp[(b<<9) + col] = (a0+a1)+(a2+a3);
  } else {
    int t = threadIdx.x;
    float a = fabsf(vvg[t]) + fabsf(vvg[t+256]);
    #pragma unroll
    for (int o = 32; o >= 1; o >>= 1) a += __shfl_xor(a, o);
    if ((t & 63) == 0) s_dh[t>>6] = a;
    __syncthreads();
    if (t == 0) vC[0] = s_dh[0]+s_dh[1]+s_dh[2]+s_dh[3];
  }
}

// ---- k1: deep-pipelined fused scores + unnorm-softmax + ctx partials ----
// R15: 1024 thr / 16 waves (2x8), tile 128x512, BK=32.
// B TRIPLE-buffered + A f16 dbuf; staging issued 2 steps ahead; loop barrier
// waits vmcnt(3) (the 3 loads for t+2 stay IN FLIGHT across the barrier) --
// T3+T4: never drain vmcnt to 0 in the main loop.
__global__ __launch_bounds__(1024) void fused_k(
    const float* __restrict__ enc,   // [64][2048][1024] f32
    const f16*   __restrict__ Bg,    // [128][512][8] f16
    const float* __restrict__ dp,    // [64][512]
    const float* __restrict__ vvg,   // [512]
    const float* __restrict__ vC,    // [1]
    const int*   __restrict__ mask,  // [64][2048]
    float*       __restrict__ pbuf,  // [64][2048]
    float*       __restrict__ denom, // [64][32]
    float*       __restrict__ part)  // [2048][1024]
{
  __shared__ __align__(16) f16 Bt[3][16384];   // 96 KB  [g4][col512][8]
  __shared__ __align__(16) f16 At[2][4096];    // 16 KB  [g4][row128^(g<<1)][8]
  __shared__ float s_sc[128];

  const int tid  = threadIdx.x;
  const int lane = tid & 63;
  const int wave = tid >> 6;                   // 0..15
  const int wr   = wave >> 3;                  // 0..1  (64-row half)
  const int wc   = wave & 7;                   // 0..7  (64-col slice)
  const int b    = blockIdx.x >> 4;
  const int s0   = (blockIdx.x & 15) << 7;

  if (tid < 128) s_sc[tid] = 0.0f;

  // A staging: arow = tid>>3 (0..127), akq = tid&7 (4-float octet)
  const int arow = tid >> 3;
  const int akq  = tid & 7;
  const int kg   = akq >> 1, par = akq & 1;
  const float* aG = enc + ((size_t)(b*S_ + s0 + arow) << 10) + (akq << 2);
  const int aDst = (kg<<10) + ((arow ^ (kg<<1))<<3) + (par<<2);

  const int r16 = lane & 15, g = lane >> 4;

  f32x4 acc[4][4] = {};

  auto stageB = [&](int buf, int t){
    const f16* src = Bg + ((size_t)t << 14);
    #pragma unroll
    for (int i = 0; i < 2; ++i){
      int slot = (i<<10) + tid;
      __builtin_amdgcn_global_load_lds(
          (const __attribute__((address_space(1))) void*)(src + (slot<<3)),
          (__attribute__((address_space(3))) void*)(&Bt[buf][slot<<3]),
          16, 0, 0);
    }
  };
  auto loadA = [&](int t)->f32x4 { return *(const f32x4*)(aG + (t<<5)); };
  auto putA  = [&](f32x4 a, int buf){
    f16x4 h; h[0]=(f16)a[0]; h[1]=(f16)a[1]; h[2]=(f16)a[2]; h[3]=(f16)a[3];
    *(f16x4*)&At[buf][aDst] = h;
  };

  // prologue: stage tiles 0 and 1; A(0) into LDS
  stageB(0, 0);
  f32x4 aR0 = loadA(0);
  stageB(1, 1);
  f32x4 aHold = loadA(1);
  asm volatile("s_waitcnt vmcnt(3)" ::: "memory");   // tile0 trio retired
  __builtin_amdgcn_sched_barrier(0);
  putA(aR0, 0);
  asm volatile("s_waitcnt lgkmcnt(0)" ::: "memory");
  __builtin_amdgcn_sched_barrier(0);
  __builtin_amdgcn_s_barrier();
  __builtin_amdgcn_sched_barrier(0);

  for (int t = 0; t < 32; ++t){
    f32x4 aNew = aHold;
    if (t <= 29){
      stageB((t+2)%3, t+2);          // 2 vmem -> in flight across barrier
      aNew = loadA(t+2);             // 1 vmem -> in flight across barrier
    }
    if (t <= 30) putA(aHold, (t+1)&1);   // A(t+1); compiler waits its load only

    const f16* Bb = &Bt[t%3][0];
    const f16* Ab = &At[t&1][0];
    f16x8 af[4];
    #pragma unroll
    for (int m = 0; m < 4; ++m)
      af[m] = *(const f16x8*)&Ab[(g<<10) + ((((wr<<6)+(m<<4)+r16) ^ (g<<1))<<3)];
    #pragma unroll
    for (int n = 0; n < 4; ++n){
      f16x8 bf = *(const f16x8*)&Bb[(g<<12) + (((wc<<6)+(n<<4)+r16)<<3)];
      #pragma unroll
      for (int m = 0; m < 4; ++m)
        acc[m][n] = __builtin_amdgcn_mfma_f32_16x16x32_f16(af[m], bf, acc[m][n], 0, 0, 0);
    }

    if (t < 31){
      if (t <= 29){
        // the 3 loads for (t+2) remain in flight; (t+1)'s are retired
        asm volatile("s_waitcnt vmcnt(3) lgkmcnt(0)" ::: "memory");
      } else {
        asm volatile("s_waitcnt vmcnt(0) lgkmcnt(0)" ::: "memory");
      }
      __builtin_amdgcn_sched_barrier(0);
      __builtin_amdgcn_s_barrier();
      __builtin_amdgcn_sched_barrier(0);
    }
    aHold = aNew;
  }

  // epilogue: e = tanh(acc + dp[col]); row-score += v[col]*e
  float dpv[4], vvv[4];
  #pragma unroll
  for (int n = 0; n < 4; ++n){
    int c = (wc<<6) + (n<<4) + r16;
    dpv[n] = dp[(b<<9) + c];
    vvv[n] = vvg[c];
  }
  float sp[4][4];
  #pragma unroll
  for (int m = 0; m < 4; ++m)
    #pragma unroll
    for (int r = 0; r < 4; ++r) sp[m][r] = 0.f;
  #pragma unroll
  for (int m = 0; m < 4; ++m)
    #pragma unroll
    for (int n = 0; n < 4; ++n)
      #pragma unroll
      for (int r = 0; r < 4; ++r){
        float e = fast_tanh(acc[m][n][r] + dpv[n]);
        sp[m][r] += vvv[n]*e;
      }
  #pragma unroll
  for (int m = 0; m < 4; ++m)
    #pragma unroll
    for (int r = 0; r < 4; ++r){
      float x = sp[m][r];
      x += __shfl_xor(x, 1);
      x += __shfl_xor(x, 2);
      x += __shfl_xor(x, 4);
      x += __shfl_xor(x, 8);
      if (r16 == 0) atomicAdd(&s_sc[(wr<<6) + (m<<4) + (g<<2) + r], x);
    }
  __syncthreads();

  // p = mask ? exp(score - C) : 0 ; pbuf + per-64-chunk denom
  const float C = vC[0];
  if (tid < 128){
    float s = s_sc[tid];
    int mk = mask[(b<<11) + s0 + tid];
    float p = mk ? __expf(s - C) : 0.0f;
    s_sc[tid] = p;
    pbuf[(b<<11) + s0 + tid] = p;
    float d = p;
    #pragma unroll
    for (int o = 32; o >= 1; o >>= 1) d += __shfl_xor(d, o);
    if (lane == 0) denom[(b<<5) + ((blockIdx.x & 15)<<1) + wave] = d;
  }
  __syncthreads();

  // ctx partials: two 64-row chunks; threads 0..511 -> chunk 0, 512.. -> chunk 1
  {
    const int half = tid >> 9;           // 0/1
    const int ttid = tid & 511;          // float2 slot
    const float2* e2 = (const float2*)(enc + ((size_t)(b*S_ + s0 + (half<<6)) << 10)) + ttid;
    float ax = 0.f, ay = 0.f;
    #pragma unroll 4
    for (int s = 0; s < 64; ++s){
      float w = s_sc[(half<<6) + s];
      float2 x = e2[s*512];
      ax += w * x.x; ay += w * x.y;
    }
    int slice = (b<<5) + ((blockIdx.x & 15)<<1) + half;
    float2* pp = (float2*)part + ((size_t)slice << 9) + ttid;
    *pp = make_float2(ax, ay);
  }
}

// ---- k2: combine: D = sum denom; ctx = sum part / D; attn = pbuf / D ----
__global__ __launch_bounds__(256) void combine_k(const float* __restrict__ part,
                                                 const float* __restrict__ denom,
                                                 const float* __restrict__ pbuf,
                                                 float* __restrict__ ctx,
                                                 float* __restrict__ attn){
  const int b = blockIdx.x, tid = threadIdx.x;
  float D = 0.f;
  #pragma unroll
  for (int c = 0; c < 32; ++c) D += denom[(b<<5) + c];
  D = fmaxf(D, 1e-37f);
  const float inv = 1.0f / D;

  f32x4 acc = {0.f,0.f,0.f,0.f};
  const f32x4* p4 = (const f32x4*)part;
  #pragma unroll
  for (int c = 0; c < 32; ++c)
    acc += p4[(((b<<5)+c)<<8) + tid];
  ((f32x4*)ctx)[(b<<8) + tid] = acc * inv;

  #pragma unroll
  for (int i = 0; i < 8; ++i){
    int s = tid + (i<<8);
    attn[(b<<11) + s] = pbuf[(b<<11) + s] * inv;
  }
}

extern "C" void kernel_launch(void* const* d_in, const int* in_sizes, int n_in,
                              void* d_out, int out_size, void* d_ws, size_t ws_size,
                              hipStream_t stream){
  (void)in_sizes; (void)n_in; (void)out_size;
  const size_t WS_NEED = 1712384u + 8388608u;   // ~9.63 MB
  if (ws_size < WS_NEED) return;

  const float* dec_h = (const float*)d_in[0];
  const float* enc   = (const float*)d_in[1];
  const int*   mask  = (const int*)d_in[2];
  const float* Wd    = (const float*)d_in[3];
  const float* We    = (const float*)d_in[4];
  const float* v     = (const float*)d_in[5];
  float* out  = (float*)d_out;
  float* ctx  = out;                       // [64][1024]
  float* attn = out + B_*2*H_;             // [64][2048]

  char* ws = (char*)d_ws;
  f16*   Bg     = (f16*)ws;
  float* dproj  = (float*)(ws + 1048576);
  float* vC     = (float*)(ws + 1179648);
  float* pbuf   = (float*)(ws + 1179904);
  float* denom  = (float*)(ws + 1704192);
  float* part   = (float*)(ws + 1712384);

  prep_k   <<<2177, 256, 0, stream>>>(We, Bg, dec_h, Wd, dproj, v, vC);
  fused_k  <<<1024, 1024, 0, stream>>>(enc, Bg, dproj, v, vC, mask, pbuf, denom, part);
  combine_k<<<B_, 256, 0, stream>>>(part, denom, pbuf, ctx, attn);
}

// Round 16
// 301.028 us; speedup vs baseline: 1.1093x; 1.0517x over previous
//
#include <hip/hip_runtime.h>

typedef _Float16 f16;
typedef f16  f16x4 __attribute__((ext_vector_type(4)));
typedef f16  f16x8 __attribute__((ext_vector_type(8)));
typedef float f32x4 __attribute__((ext_vector_type(4)));

#define B_  64
#define S_  2048
#define H_  512
#define K_  1024   // 2H

__device__ __forceinline__ float fast_tanh(float x){
  float ax = fabsf(x);
  float t  = __expf(-2.0f*ax);
  float r  = (1.0f - t) / (1.0f + t);
  return x < 0.0f ? -r : r;
}

// ---- k0: fused {We repack} + {dec_proj GEMV} + {C = sum|v|} ---------------
__global__ __launch_bounds__(256) void prep_k(const float* __restrict__ We,
                                              f16* __restrict__ Bg,
                                              const float* __restrict__ dh,
                                              const float* __restrict__ Wd,
                                              float* __restrict__ dp,
                                              const float* __restrict__ vvg,
                                              float* __restrict__ vC){
  __shared__ float s_dh[512];
  if (blockIdx.x < 2048){
    int idx = blockIdx.x*256 + threadIdx.x;      // 0..524287
    int k = idx >> 9, col = idx & 511;
    Bg[((k>>3)<<12) + (col<<3) + (k&7)] = (f16)We[idx];
  } else if (blockIdx.x < 2176){
    int idx = blockIdx.x - 2048;                 // 0..127
    int b = idx >> 1, cg = idx & 1;
    int col = (cg<<8) + threadIdx.x;
    for (int i = threadIdx.x; i < 512; i += 256) s_dh[i] = dh[(b<<9) + i];
    __syncthreads();
    float a0=0.f,a1=0.f,a2=0.f,a3=0.f;
    for (int k = 0; k < 512; k += 4){
      a0 += s_dh[k+0]*Wd[(k+0)*512 + col];
      a1 += s_dh[k+1]*Wd[(k+1)*512 + col];
      a2 += s_dh[k+2]*Wd[(k+2)*512 + col];
      a3 += s_dh[k+3]*Wd[(k+3)*512 + col];
    }
    dp[(b<<9) + col] = (a0+a1)+(a2+a3);
  } else {
    int t = threadIdx.x;
    float a = fabsf(vvg[t]) + fabsf(vvg[t+256]);
    #pragma unroll
    for (int o = 32; o >= 1; o >>= 1) a += __shfl_xor(a, o);
    if ((t & 63) == 0) s_dh[t>>6] = a;
    __syncthreads();
    if (t == 0) vC[0] = s_dh[0]+s_dh[1]+s_dh[2]+s_dh[3];
  }
}

// ---- k1: fused scores + unnorm-softmax + ctx partials ----
// R16: per-wave-PRIVATE B staging (each wave gload_lds's only the 4 KB
// col-slice it reads) -> no cross-wave vmem dependency -> loop barrier is
// lgkmcnt(0)-only (A visibility). B(t) readiness comes free from putA's
// FIFO wait on A(t+1). T5 setprio around MFMA cluster.
__global__ __launch_bounds__(512, 2) void fused_k(
    const float* __restrict__ enc,   // [64][2048][1024] f32
    const f16*   __restrict__ Bg,    // [128][512][8] f16
    const float* __restrict__ dp,    // [64][512]
    const float* __restrict__ vvg,   // [512]
    const float* __restrict__ vC,    // [1]
    const int*   __restrict__ mask,  // [64][2048]
    float*       __restrict__ pbuf,  // [64][2048]
    float*       __restrict__ denom, // [64][32]
    float*       __restrict__ part)  // [2048][1024]
{
  __shared__ __align__(16) f16 At[2][2048];    // [kgrp4][row64^(kgrp<<1)][8]
  __shared__ __align__(16) f16 Bt[2][16384];   // [kgrp4][col512][8]
  __shared__ float s_sc[64];

  const int tid  = threadIdx.x;
  const int lane = tid & 63;
  const int wave = tid >> 6;
  const int b    = blockIdx.x >> 5;
  const int s0   = (blockIdx.x & 31) << 6;

  if (tid < 64) s_sc[tid] = 0.0f;

  // A staging map (R8-proven): 8 threads/row, 4 f32 -> f16 each, XOR swizzle
  const int arow = tid >> 3;
  const int akq  = tid & 7;
  const int kgrp = akq >> 1, apar = akq & 1;
  const float* aG = enc + ((size_t)(b*S_ + s0 + arow) << 10) + (akq << 2);
  const int aDst = (kgrp<<9) + ((arow ^ (kgrp<<1))<<3) + (apar<<2);

  const int r16 = lane & 15, g = lane >> 4;
  const int aFrag = (g<<9) + ((r16 ^ (g<<1))<<3);
  const int colb  = wave << 6;

  f32x4 acc[4][4] = {};

  // per-wave-private B staging: wave loads its own 64-col slice, all 4 kgrps
  auto stageB = [&](int buf, int kt){
    const f16* srcBase = Bg + ((size_t)kt << 14);
    #pragma unroll
    for (int gg = 0; gg < 4; ++gg){
      int off = (gg<<12) + (colb<<3) + (lane<<3);   // halves
      __builtin_amdgcn_global_load_lds(
          (const __attribute__((address_space(1))) void*)(srcBase + off),
          (__attribute__((address_space(3))) void*)(&Bt[buf][off]),
          16, 0, 0);
    }
  };
  auto loadA = [&](int t)->f32x4 { return *(const f32x4*)(aG + (t<<5)); };
  auto putA  = [&](f32x4 a4, int buf){
    f16x4 h4; h4[0]=(f16)a4[0]; h4[1]=(f16)a4[1]; h4[2]=(f16)a4[2]; h4[3]=(f16)a4[3];
    *(f16x4*)&At[buf][aDst] = h4;
  };

  // prologue: B(0),A(0) staged; A(1) in flight; barrier = lgkm only
  stageB(0, 0);
  f32x4 a0 = loadA(0);
  stageB(1, 1);
  f32x4 aCur = loadA(1);
  putA(a0, 0);                       // waits a0 -> retires own B(0) gloads too
  asm volatile("s_waitcnt lgkmcnt(0)" ::: "memory");
  __builtin_amdgcn_sched_barrier(0);
  __builtin_amdgcn_s_barrier();
  __builtin_amdgcn_sched_barrier(0);

  for (int t = 0; t < 32; ++t){
    const int cur = t & 1;
    if (t < 31){
      stageB(cur^1, t+1);            // 4 vmem, own region (last read by this
                                     // wave at t-1, lgkm-drained since)
      f32x4 aNext = loadA(t+2 <= 31 ? t+2 : 31);
      putA(aCur, cur^1);             // FIFO: waits A(t+1) -> own B(t) retired
      aCur = aNext;
    } else {
      asm volatile("s_waitcnt vmcnt(1)" ::: "memory");  // retire B(31); dummy A may fly
      __builtin_amdgcn_sched_barrier(0);
    }
    // compute step t (reads only this wave's B slice + shared A)
    f16x8 af[4], bfr[4];
    #pragma unroll
    for (int n = 0; n < 4; ++n)
      bfr[n] = *(const f16x8*)&Bt[cur][(g<<12) + ((colb + (n<<4) + r16)<<3)];
    #pragma unroll
    for (int m = 0; m < 4; ++m)
      af[m] = *(const f16x8*)&At[cur][aFrag + (m<<7)];
    __builtin_amdgcn_s_setprio(1);
    #pragma unroll
    for (int m = 0; m < 4; ++m)
      #pragma unroll
      for (int n = 0; n < 4; ++n)
        acc[m][n] = __builtin_amdgcn_mfma_f32_16x16x32_f16(af[m], bfr[n], acc[m][n], 0, 0, 0);
    __builtin_amdgcn_s_setprio(0);
    if (t < 31){
      // A-visibility barrier only: no vmem drain
      asm volatile("s_waitcnt lgkmcnt(0)" ::: "memory");
      __builtin_amdgcn_sched_barrier(0);
      __builtin_amdgcn_s_barrier();
      __builtin_amdgcn_sched_barrier(0);
    }
  }

  // epilogue: e = tanh(acc + dp[col]); score_row += v[col]*e
  float dpv[4], vvv[4];
  #pragma unroll
  for (int n = 0; n < 4; ++n){
    int c = colb + (n<<4) + r16;
    dpv[n] = dp[(b<<9) + c];
    vvv[n] = vvg[c];
  }
  float sp[4][4];
  #pragma unroll
  for (int m = 0; m < 4; ++m)
    #pragma unroll
    for (int r = 0; r < 4; ++r) sp[m][r] = 0.f;
  #pragma unroll
  for (int m = 0; m < 4; ++m)
    #pragma unroll
    for (int n = 0; n < 4; ++n)
      #pragma unroll
      for (int r = 0; r < 4; ++r){
        float e = fast_tanh(acc[m][n][r] + dpv[n]);
        sp[m][r] += vvv[n]*e;
      }
  #pragma unroll
  for (int m = 0; m < 4; ++m)
    #pragma unroll
    for (int r = 0; r < 4; ++r){
      float x = sp[m][r];
      x += __shfl_xor(x, 1);
      x += __shfl_xor(x, 2);
      x += __shfl_xor(x, 4);
      x += __shfl_xor(x, 8);
      if (r16 == 0) atomicAdd(&s_sc[(m<<4) + (g<<2) + r], x);
    }
  __syncthreads();

  // p = mask ? exp(score - C) : 0 ; denom partial; overwrite s_sc with p
  const float C = vC[0];
  if (tid < 64){
    float s = s_sc[tid];
    int mk = mask[(b<<11) + s0 + tid];
    float p = mk ? __expf(s - C) : 0.0f;
    s_sc[tid] = p;
    pbuf[(b<<11) + s0 + tid] = p;
    float d = p;
    #pragma unroll
    for (int o = 32; o >= 1; o >>= 1) d += __shfl_xor(d, o);
    if (tid == 0) denom[(b<<5) + (blockIdx.x & 31)] = d;
  }
  __syncthreads();

  // context partial: part[blk][c] = sum_{s=0..63} p_s * enc[b][s0+s][c]
  {
    const float2* e2 = (const float2*)(enc + ((size_t)(b*S_ + s0) << 10)) + tid;
    float ax = 0.f, ay = 0.f;
    #pragma unroll 4
    for (int s = 0; s < 64; ++s){
      float w = s_sc[s];
      float2 x = e2[s*512];
      ax += w * x.x; ay += w * x.y;
    }
    float2* pp = (float2*)part + ((size_t)blockIdx.x << 9) + tid;
    *pp = make_float2(ax, ay);
  }
}

// ---- k2: combine: D = sum denom; ctx = sum part / D; attn = pbuf / D ----
__global__ __launch_bounds__(256) void combine_k(const float* __restrict__ part,
                                                 const float* __restrict__ denom,
                                                 const float* __restrict__ pbuf,
                                                 float* __restrict__ ctx,
                                                 float* __restrict__ attn){
  const int b = blockIdx.x, tid = threadIdx.x;
  float D = 0.f;
  #pragma unroll
  for (int c = 0; c < 32; ++c) D += denom[(b<<5) + c];
  D = fmaxf(D, 1e-37f);
  const float inv = 1.0f / D;

  f32x4 acc = {0.f,0.f,0.f,0.f};
  const f32x4* p4 = (const f32x4*)part;
  #pragma unroll
  for (int c = 0; c < 32; ++c)
    acc += p4[(((b<<5)+c)<<8) + tid];
  ((f32x4*)ctx)[(b<<8) + tid] = acc * inv;

  #pragma unroll
  for (int i = 0; i < 8; ++i){
    int s = tid + (i<<8);
    attn[(b<<11) + s] = pbuf[(b<<11) + s] * inv;
  }
}

extern "C" void kernel_launch(void* const* d_in, const int* in_sizes, int n_in,
                              void* d_out, int out_size, void* d_ws, size_t ws_size,
                              hipStream_t stream){
  (void)in_sizes; (void)n_in; (void)out_size;
  const size_t WS_NEED = 1712384u + 8388608u;   // ~9.63 MB
  if (ws_size < WS_NEED) return;

  const float* dec_h = (const float*)d_in[0];
  const float* enc   = (const float*)d_in[1];
  const int*   mask  = (const int*)d_in[2];
  const float* Wd    = (const float*)d_in[3];
  const float* We    = (const float*)d_in[4];
  const float* v     = (const float*)d_in[5];
  float* out  = (float*)d_out;
  float* ctx  = out;                       // [64][1024]
  float* attn = out + B_*2*H_;             // [64][2048]

  char* ws = (char*)d_ws;
  f16*   Bg     = (f16*)ws;
  float* dproj  = (float*)(ws + 1048576);
  float* vC     = (float*)(ws + 1179648);
  float* pbuf   = (float*)(ws + 1179904);
  float* denom  = (float*)(ws + 1704192);
  float* part   = (float*)(ws + 1712384);

  prep_k   <<<2177, 256, 0, stream>>>(We, Bg, dec_h, Wd, dproj, v, vC);
  fused_k  <<<2048, 512, 0, stream>>>(enc, Bg, dproj, v, vC, mask, pbuf, denom, part);
  combine_k<<<B_, 256, 0, stream>>>(part, denom, pbuf, ctx, attn);
}

// Round 17
// 287.676 us; speedup vs baseline: 1.1608x; 1.0464x over previous
//
#include <hip/hip_runtime.h>

typedef _Float16 f16;
typedef f16  f16x4 __attribute__((ext_vector_type(4)));
typedef f16  f16x8 __attribute__((ext_vector_type(8)));
typedef float f32x4 __attribute__((ext_vector_type(4)));

#define B_  64
#define S_  2048
#define H_  512
#define K_  1024   // 2H

__device__ __forceinline__ float fast_tanh(float x){
  float ax = fabsf(x);
  float t  = __expf(-2.0f*ax);
  float r  = (1.0f - t) / (1.0f + t);
  return x < 0.0f ? -r : r;
}

// ---- k0: fused {We repack} + {dec_proj GEMV} + {C = sum|v|} ---------------
__global__ __launch_bounds__(256) void prep_k(const float* __restrict__ We,
                                              f16* __restrict__ Bg,
                                              const float* __restrict__ dh,
                                              const float* __restrict__ Wd,
                                              float* __restrict__ dp,
                                              const float* __restrict__ vvg,
                                              float* __restrict__ vC){
  __shared__ float s_dh[512];
  if (blockIdx.x < 2048){
    int idx = blockIdx.x*256 + threadIdx.x;      // 0..524287
    int k = idx >> 9, col = idx & 511;
    Bg[((k>>3)<<12) + (col<<3) + (k&7)] = (f16)We[idx];
  } else if (blockIdx.x < 2176){
    int idx = blockIdx.x - 2048;                 // 0..127
    int b = idx >> 1, cg = idx & 1;
    int col = (cg<<8) + threadIdx.x;
    for (int i = threadIdx.x; i < 512; i += 256) s_dh[i] = dh[(b<<9) + i];
    __syncthreads();
    float a0=0.f,a1=0.f,a2=0.f,a3=0.f;
    for (int k = 0; k < 512; k += 4){
      a0 += s_dh[k+0]*Wd[(k+0)*512 + col];
      a1 += s_dh[k+1]*Wd[(k+1)*512 + col];
      a2 += s_dh[k+2]*Wd[(k+2)*512 + col];
      a3 += s_dh[k+3]*Wd[(k+3)*512 + col];
    }
    dp[(b<<9) + col] = (a0+a1)+(a2+a3);
  } else {
    int t = threadIdx.x;
    float a = fabsf(vvg[t]) + fabsf(vvg[t+256]);
    #pragma unroll
    for (int o = 32; o >= 1; o >>= 1) a += __shfl_xor(a, o);
    if ((t & 63) == 0) s_dh[t>>6] = a;
    __syncthreads();
    if (t == 0) vC[0] = s_dh[0]+s_dh[1]+s_dh[2]+s_dh[3];
  }
}

// ---- k1: fused scores + unnorm-softmax + ctx partials ----
// R17: B fragments read REGISTER-DIRECT from L2 (Bg is 1 MB, L2/L3-resident;
// don't LDS-stage cache-fit data). No Bt, no B gload_lds, no vmem in the
// loop barrier. A (HBM-streamed, shared by all waves) keeps LDS dbuf +
// depth-2 register prefetch; barrier is lgkm-only so A(t+2) flies across it.
__global__ __launch_bounds__(512, 2) void fused_k(
    const float* __restrict__ enc,   // [64][2048][1024] f32
    const f16*   __restrict__ Bg,    // [128][512][8] f16
    const float* __restrict__ dp,    // [64][512]
    const float* __restrict__ vvg,   // [512]
    const float* __restrict__ vC,    // [1]
    const int*   __restrict__ mask,  // [64][2048]
    float*       __restrict__ pbuf,  // [64][2048]
    float*       __restrict__ denom, // [64][32]
    float*       __restrict__ part)  // [2048][1024]
{
  __shared__ __align__(16) f16 At[2][2048];    // [kgrp4][row64^(kgrp<<1)][8]
  __shared__ float s_sc[64];

  const int tid  = threadIdx.x;
  const int lane = tid & 63;
  const int wave = tid >> 6;
  const int b    = blockIdx.x >> 5;
  const int s0   = (blockIdx.x & 31) << 6;

  if (tid < 64) s_sc[tid] = 0.0f;

  // A staging map (R8-proven): 8 threads/row, 4 f32 -> f16 each, XOR swizzle
  const int arow = tid >> 3;
  const int akq  = tid & 7;
  const int kgrp = akq >> 1, apar = akq & 1;
  const float* aG = enc + ((size_t)(b*S_ + s0 + arow) << 10) + (akq << 2);
  const int aDst = (kgrp<<9) + ((arow ^ (kgrp<<1))<<3) + (apar<<2);

  const int r16 = lane & 15, g = lane >> 4;
  const int aFrag = (g<<9) + ((r16 ^ (g<<1))<<3);
  const int colb  = wave << 6;

  // B fragment base: lane's 16B slice; step t at offset t*16384 halves
  const f16* bP = Bg + (g<<12) + ((colb + r16)<<3);

  f32x4 acc[4][4] = {};

  auto loadA = [&](int t)->f32x4 { return *(const f32x4*)(aG + (t<<5)); };
  auto putA  = [&](f32x4 a4, int buf){
    f16x4 h4; h4[0]=(f16)a4[0]; h4[1]=(f16)a4[1]; h4[2]=(f16)a4[2]; h4[3]=(f16)a4[3];
    *(f16x4*)&At[buf][aDst] = h4;
  };

  // prologue: A(0) staged; A(1) in flight; barrier = lgkm only
  {
    f32x4 a0 = loadA(0);
    putA(a0, 0);                     // waits a0
  }
  f32x4 aCur = loadA(1);
  asm volatile("s_waitcnt lgkmcnt(0)" ::: "memory");
  __builtin_amdgcn_sched_barrier(0);
  __builtin_amdgcn_s_barrier();
  __builtin_amdgcn_sched_barrier(0);

  for (int t = 0; t < 32; ++t){
    const int cur = t & 1;
    f32x4 aNext;
    if (t < 31){
      putA(aCur, cur^1);             // waits aCur (oldest outstanding vmem)
    }
    // B(t) fragments: register-direct from L2 (issued before the A prefetch
    // so the MFMA wait on them does NOT drain the newer A load)
    f16x8 bfr[4];
    #pragma unroll
    for (int n = 0; n < 4; ++n)
      bfr[n] = *(const f16x8*)(bP + (n<<7));
    if (t < 31){
      aNext = loadA(t+2 <= 31 ? t+2 : 31);   // newest; stays in flight
    }
    // A fragments from LDS + MFMA cluster
    __builtin_amdgcn_s_setprio(1);
    #pragma unroll
    for (int m = 0; m < 4; ++m){
      f16x8 af = *(const f16x8*)&At[cur][aFrag + (m<<7)];
      #pragma unroll
      for (int n = 0; n < 4; ++n)
        acc[m][n] = __builtin_amdgcn_mfma_f32_16x16x32_f16(af, bfr[n], acc[m][n], 0, 0, 0);
    }
    __builtin_amdgcn_s_setprio(0);
    if (t < 31){
      // A-visibility barrier only: no vmem drain (A(t+2) stays in flight)
      asm volatile("s_waitcnt lgkmcnt(0)" ::: "memory");
      __builtin_amdgcn_sched_barrier(0);
      __builtin_amdgcn_s_barrier();
      __builtin_amdgcn_sched_barrier(0);
      aCur = aNext;
    }
    bP += (1<<14);                   // advance to next K-step's B panel
  }

  // epilogue: e = tanh(acc + dp[col]); score_row += v[col]*e
  float dpv[4], vvv[4];
  #pragma unroll
  for (int n = 0; n < 4; ++n){
    int c = colb + (n<<4) + r16;
    dpv[n] = dp[(b<<9) + c];
    vvv[n] = vvg[c];
  }
  float sp[4][4];
  #pragma unroll
  for (int m = 0; m < 4; ++m)
    #pragma unroll
    for (int r = 0; r < 4; ++r) sp[m][r] = 0.f;
  #pragma unroll
  for (int m = 0; m < 4; ++m)
    #pragma unroll
    for (int n = 0; n < 4; ++n)
      #pragma unroll
      for (int r = 0; r < 4; ++r){
        float e = fast_tanh(acc[m][n][r] + dpv[n]);
        sp[m][r] += vvv[n]*e;
      }
  #pragma unroll
  for (int m = 0; m < 4; ++m)
    #pragma unroll
    for (int r = 0; r < 4; ++r){
      float x = sp[m][r];
      x += __shfl_xor(x, 1);
      x += __shfl_xor(x, 2);
      x += __shfl_xor(x, 4);
      x += __shfl_xor(x, 8);
      if (r16 == 0) atomicAdd(&s_sc[(m<<4) + (g<<2) + r], x);
    }
  __syncthreads();

  // p = mask ? exp(score - C) : 0 ; denom partial; overwrite s_sc with p
  const float C = vC[0];
  if (tid < 64){
    float s = s_sc[tid];
    int mk = mask[(b<<11) + s0 + tid];
    float p = mk ? __expf(s - C) : 0.0f;
    s_sc[tid] = p;
    pbuf[(b<<11) + s0 + tid] = p;
    float d = p;
    #pragma unroll
    for (int o = 32; o >= 1; o >>= 1) d += __shfl_xor(d, o);
    if (tid == 0) denom[(b<<5) + (blockIdx.x & 31)] = d;
  }
  __syncthreads();

  // context partial: part[blk][c] = sum_{s=0..63} p_s * enc[b][s0+s][c]
  {
    const float2* e2 = (const float2*)(enc + ((size_t)(b*S_ + s0) << 10)) + tid;
    float ax = 0.f, ay = 0.f;
    #pragma unroll 4
    for (int s = 0; s < 64; ++s){
      float w = s_sc[s];
      float2 x = e2[s*512];
      ax += w * x.x; ay += w * x.y;
    }
    float2* pp = (float2*)part + ((size_t)blockIdx.x << 9) + tid;
    *pp = make_float2(ax, ay);
  }
}

// ---- k2: combine: D = sum denom; ctx = sum part / D; attn = pbuf / D ----
__global__ __launch_bounds__(256) void combine_k(const float* __restrict__ part,
                                                 const float* __restrict__ denom,
                                                 const float* __restrict__ pbuf,
                                                 float* __restrict__ ctx,
                                                 float* __restrict__ attn){
  const int b = blockIdx.x, tid = threadIdx.x;
  float D = 0.f;
  #pragma unroll
  for (int c = 0; c < 32; ++c) D += denom[(b<<5) + c];
  D = fmaxf(D, 1e-37f);
  const float inv = 1.0f / D;

  f32x4 acc = {0.f,0.f,0.f,0.f};
  const f32x4* p4 = (const f32x4*)part;
  #pragma unroll
  for (int c = 0; c < 32; ++c)
    acc += p4[(((b<<5)+c)<<8) + tid];
  ((f32x4*)ctx)[(b<<8) + tid] = acc * inv;

  #pragma unroll
  for (int i = 0; i < 8; ++i){
    int s = tid + (i<<8);
    attn[(b<<11) + s] = pbuf[(b<<11) + s] * inv;
  }
}

extern "C" void kernel_launch(void* const* d_in, const int* in_sizes, int n_in,
                              void* d_out, int out_size, void* d_ws, size_t ws_size,
                              hipStream_t stream){
  (void)in_sizes; (void)n_in; (void)out_size;
  const size_t WS_NEED = 1712384u + 8388608u;   // ~9.63 MB
  if (ws_size < WS_NEED) return;

  const float* dec_h = (const float*)d_in[0];
  const float* enc   = (const float*)d_in[1];
  const int*   mask  = (const int*)d_in[2];
  const float* Wd    = (const float*)d_in[3];
  const float* We    = (const float*)d_in[4];
  const float* v     = (const float*)d_in[5];
  float* out  = (float*)d_out;
  float* ctx  = out;                       // [64][1024]
  float* attn = out + B_*2*H_;             // [64][2048]

  char* ws = (char*)d_ws;
  f16*   Bg     = (f16*)ws;
  float* dproj  = (float*)(ws + 1048576);
  float* vC     = (float*)(ws + 1179648);
  float* pbuf   = (float*)(ws + 1179904);
  float* denom  = (float*)(ws + 1704192);
  float* part   = (float*)(ws + 1712384);

  prep_k   <<<2177, 256, 0, stream>>>(We, Bg, dec_h, Wd, dproj, v, vC);
  fused_k  <<<2048, 512, 0, stream>>>(enc, Bg, dproj, v, vC, mask, pbuf, denom, part);
  combine_k<<<B_, 256, 0, stream>>>(part, denom, pbuf, ctx, attn);
}